// Round 4
// baseline (1066.333 us; speedup 1.0000x reference)
//
#include <hip/hip_runtime.h>
#include <cstdint>
#include <cstddef>

#define S_LEN 4096
#define HID   3584
#define NH    16
#define NKV   8
#define HD    256
#define QSZ   (NH*HD)            // 4096
#define KVSZ  (NKV*HD)           // 2048
#define QKV_N (QSZ + 2*KVSZ)     // 8192
#define WINDOW 2047

typedef unsigned short u16;
typedef __bf16 bf16x8 __attribute__((ext_vector_type(8)));
typedef u16    u16x8  __attribute__((ext_vector_type(8)));
typedef u16    u16x4  __attribute__((ext_vector_type(4)));
typedef float  f32x4  __attribute__((ext_vector_type(4)));

__device__ inline float bf2f(u16 u) {
    union { unsigned u; float f; } v; v.u = ((unsigned)u) << 16; return v.f;
}
__device__ inline u16 f2bf(float f) {
    union { float f; unsigned u; } v; v.f = f;
    return (u16)((v.u + 0x7FFF + ((v.u >> 16) & 1)) >> 16);
}
__device__ inline float fast_tanh(float x) {
    x = fminf(fmaxf(x, -20.f), 20.f);
    float e = __expf(2.f * x);
    return 1.f - 2.f / (e + 1.f);
}

// ---- async global->LDS (width 16): LDS dest = wave-uniform base + lane*16 --
typedef const __attribute__((address_space(1))) unsigned GU32;
typedef __attribute__((address_space(3))) unsigned LU32;
__device__ inline void gll16(const void* g, const void* l) {
    __builtin_amdgcn_global_load_lds((GU32*)(size_t)g,
                                     (LU32*)(unsigned)(size_t)l, 16, 0, 0);
}

// ---------------- fp32 -> bf16 cast (vectorized) ----------------
__global__ __launch_bounds__(256)
void cast_f32_bf16(const float* __restrict__ src, u16* __restrict__ dst, int n4) {
    int i = blockIdx.x * blockDim.x + threadIdx.x;
    if (i >= n4) return;
    float4 v = ((const float4*)src)[i];
    u16x4 o;
    o[0] = f2bf(v.x); o[1] = f2bf(v.y); o[2] = f2bf(v.z); o[3] = f2bf(v.w);
    ((u16x4*)dst)[i] = o;
}

// ---------------- bf16 GEMM, C[m,n] = sum_k A[m,k]*B[n,k]  (both K-major) ----
template<int BF16OUT>
__global__ __launch_bounds__(256)
void gemm_bt(const u16* __restrict__ A, const u16* __restrict__ B,
             void* __restrict__ Cv, int M, int N, int K) {
    __shared__ u16 lA[128 * 32];
    __shared__ u16 lB[128 * 32];
    const int tid  = threadIdx.x;
    const int lane = tid & 63, wave = tid >> 6;
    const int quad = lane >> 4, l16 = lane & 15;
    const int m0 = blockIdx.y * 128, n0 = blockIdx.x * 128;
    const int wm = (wave & 1) * 64, wn = (wave >> 1) * 64;

    f32x4 zero = {0.f, 0.f, 0.f, 0.f};
    f32x4 acc[4][4];
#pragma unroll
    for (int i = 0; i < 4; ++i)
#pragma unroll
        for (int j = 0; j < 4; ++j) acc[i][j] = zero;

    const int c0 = tid, c1 = tid + 256;
    const int r0 = c0 >> 2, cc0 = (c0 & 3) * 8;
    const int r1 = c1 >> 2, cc1 = (c1 & 3) * 8;
    const u16* A0 = A + (size_t)(m0 + r0) * K + cc0;
    const u16* A1 = A + (size_t)(m0 + r1) * K + cc1;
    const u16* B0 = B + (size_t)(n0 + r0) * K + cc0;
    const u16* B1 = B + (size_t)(n0 + r1) * K + cc1;

    u16x8 ra0 = *(const u16x8*)A0;
    u16x8 ra1 = *(const u16x8*)A1;
    u16x8 rb0 = *(const u16x8*)B0;
    u16x8 rb1 = *(const u16x8*)B1;

    for (int k0 = 0; k0 < K; k0 += 32) {
        __syncthreads();
        *(u16x8*)(&lA[c0 * 8]) = ra0;
        *(u16x8*)(&lA[c1 * 8]) = ra1;
        *(u16x8*)(&lB[c0 * 8]) = rb0;
        *(u16x8*)(&lB[c1 * 8]) = rb1;
        __syncthreads();
        int kn = k0 + 32;
        if (kn < K) {
            ra0 = *(const u16x8*)(A0 + kn);
            ra1 = *(const u16x8*)(A1 + kn);
            rb0 = *(const u16x8*)(B0 + kn);
            rb1 = *(const u16x8*)(B1 + kn);
        }
        bf16x8 af[4], bfr[4];
#pragma unroll
        for (int mt = 0; mt < 4; ++mt)
            af[mt] = *(const bf16x8*)(&lA[(wm + mt * 16 + l16) * 32 + quad * 8]);
#pragma unroll
        for (int nt = 0; nt < 4; ++nt)
            bfr[nt] = *(const bf16x8*)(&lB[(wn + nt * 16 + l16) * 32 + quad * 8]);
#pragma unroll
        for (int mt = 0; mt < 4; ++mt)
#pragma unroll
            for (int nt = 0; nt < 4; ++nt)
                acc[mt][nt] = __builtin_amdgcn_mfma_f32_16x16x32_bf16(
                    af[mt], bfr[nt], acc[mt][nt], 0, 0, 0);
    }

#pragma unroll
    for (int mt = 0; mt < 4; ++mt)
#pragma unroll
        for (int nt = 0; nt < 4; ++nt)
#pragma unroll
            for (int r = 0; r < 4; ++r) {
                int row = m0 + wm + mt * 16 + quad * 4 + r;
                int col = n0 + wn + nt * 16 + l16;
                float v = acc[mt][nt][r];
                if (BF16OUT) ((u16*)Cv)[(size_t)row * N + col] = f2bf(v);
                else         ((float*)Cv)[(size_t)row * N + col] = v;
            }
}

// ---------------- RoPE (NeoX) + split + per-head relayout (Q,K only) --------
__global__ __launch_bounds__(256)
void rope_split(const u16* __restrict__ qkv, u16* __restrict__ Qb,
                u16* __restrict__ Kb) {
    const int s = blockIdx.x;
    const int t = threadIdx.x;
    const float pos = (float)s;
    const u16* row = qkv + (size_t)s * QKV_N;

    for (int p = t; p < 2048; p += 256) {      // Q: 16 heads x 128 pairs
        int h = p >> 7, d = p & 127;
        float inv = __expf(-(float)d * 0.0719557841560639f);  // ln(1e4)/128
        float ang = pos * inv, sn, cs;
        sincosf(ang, &sn, &cs);
        float x1 = bf2f(row[h * HD + d]);
        float x2 = bf2f(row[h * HD + d + 128]);
        size_t base = ((size_t)h * S_LEN + s) * HD;
        Qb[base + d]       = f2bf((x1 * cs - x2 * sn) * 0.0625f);
        Qb[base + d + 128] = f2bf((x2 * cs + x1 * sn) * 0.0625f);
    }
    for (int p = t; p < 1024; p += 256) {      // K: 8 heads x 128 pairs
        int h = p >> 7, d = p & 127;
        float inv = __expf(-(float)d * 0.0719557841560639f);
        float ang = pos * inv, sn, cs;
        sincosf(ang, &sn, &cs);
        float x1 = bf2f(row[QSZ + h * HD + d]);
        float x2 = bf2f(row[QSZ + h * HD + d + 128]);
        size_t base = ((size_t)h * S_LEN + s) * HD;
        Kb[base + d]       = f2bf(x1 * cs - x2 * sn);
        Kb[base + d + 128] = f2bf(x2 * cs + x1 * sn);
    }
}

// ---------------- V transpose: QKVb[s][...] -> Vt[h][d][s] ------------------
__global__ __launch_bounds__(256)
void transpose_v(const u16* __restrict__ qkv, u16* __restrict__ Vt) {
    const int h = blockIdx.x, s0 = blockIdx.y * 64;
    const int tid = threadIdx.x;
    __shared__ u16 t[64 * 258];
    const u16* src = qkv + QSZ + KVSZ + (size_t)h * HD;
#pragma unroll
    for (int it = 0; it < 8; ++it) {
        int idx = it * 256 + tid;                 // 2048 chunks of 8
        int sr = idx >> 5, c8 = (idx & 31) << 3;
        u16x8 v = *(const u16x8*)(src + (size_t)(s0 + sr) * QKV_N + c8);
#pragma unroll
        for (int j = 0; j < 8; ++j) t[sr * 258 + c8 + j] = v[j];
    }
    __syncthreads();
    const int lane = tid & 63, wave = tid >> 6;
    u16* dst = Vt + (size_t)h * HD * S_LEN + s0 + lane;
#pragma unroll
    for (int it = 0; it < 64; ++it) {
        int d = it * 4 + wave;
        dst[(size_t)d * S_LEN] = t[lane * 258 + d];
    }
}

// ---------------- fused sliding-window softcap attention --------------------
// 1-D grid of 512 blocks; hkv = bid & 7 so all 64 q-tile blocks of one GQA
// pair land on the SAME XCD (round-robin dispatch heuristic): the 4 MB K/V
// slab stays L2-resident -> staging loads become L2 hits, HBM re-fetch gone.
// 512 threads, 8 waves: wave>>2 = q-head of pair, wave&3 = 16-row q-slice.
// Double-buffered gll16 staging; s_setprio(1) around MFMA clusters (T5).
__global__ __launch_bounds__(512)
void attn_fused(const u16* __restrict__ Qb, const u16* __restrict__ Kb,
                const u16* __restrict__ Vt, u16* __restrict__ O) {
    const int bid = blockIdx.x;
    const int hkv = bid & 7;
    const int qt  = bid >> 3;
    const int qbase = qt * 64;
    const int tid = threadIdx.x, wave = tid >> 6, lane = tid & 63;
    const int quad = lane >> 4, l16 = lane & 15;
    const int h  = hkv * 2 + (wave >> 2);
    const int qw = qbase + (wave & 3) * 16;

    __shared__ __align__(16) u16 lK[2][32 * 256];   // 2 x 16 KB, XOR-swz rows
    __shared__ __align__(16) u16 lV[2][32 * 256];   // 2 x 16 KB (V^T, swz chunks)
    __shared__ __align__(16) u16 lP[8][16 * 40];    // per-wave P scratch

    const int qrow = qw + l16;
    bf16x8 qf[8];
    {
        const u16* qp = Qb + ((size_t)h * S_LEN + qrow) * HD + quad * 8;
#pragma unroll
        for (int f = 0; f < 8; ++f) qf[f] = *(const bf16x8*)(qp + f * 32);
    }

    // per-lane source byte offsets for the 4 gll16 calls (constant across tiles)
    int koff[2], voff[2];
#pragma unroll
    for (int i = 0; i < 2; ++i) {
        int c = i * 512 + tid;                    // chunk 0..1023
        int row = c >> 5, j = c & 31;
        koff[i] = row * 512 + ((j ^ (row & 7)) << 4);
        int d = c >> 2;
        int q = (c & 3) ^ ((d >> 1) & 3);
        voff[i] = d * (S_LEN * 2) + q * 16;       // bytes into Vt head slab
    }
    const char* Khb = (const char*)(Kb + (size_t)hkv * S_LEN * HD);
    const char* Vhb = (const char*)(Vt + (size_t)hkv * HD * S_LEN);

    // PV read base (bytes): d*64 + swizzled quad, d = dt*16 + l16
    const unsigned vrow = (unsigned)(l16 * 64)
                        + ((unsigned)(quad ^ ((l16 >> 1) & 3)) << 4);

    f32x4 zero = {0.f, 0.f, 0.f, 0.f};
    f32x4 o[16];
#pragma unroll
    for (int i = 0; i < 16; ++i) o[i] = zero;
    float m_r[4], l_r[4];
#pragma unroll
    for (int r = 0; r < 4; ++r) { m_r[r] = -1e4f; l_r[r] = 0.f; }

    const int t0 = max(0, qbase - WINDOW) >> 5;
    const int t1 = (qbase + 63) >> 5;

    // stage one 32-key tile (K + V^T) into buffer b
    auto stage = [&](int kb, int b) {
        const char* kp = Khb + ((size_t)kb << 9);   // kb rows * 512 B
        const char* vp = Vhb + ((size_t)kb << 1);   // kb * 2 B along s
#pragma unroll
        for (int i = 0; i < 2; ++i) {
            gll16(kp + koff[i], (const char*)&lK[b][0] + i * 8192 + wave * 1024);
            gll16(vp + voff[i], (const char*)&lV[b][0] + i * 8192 + wave * 1024);
        }
    };

    // prologue: fill buffer 0
    stage(t0 * 32, 0);
    asm volatile("s_waitcnt vmcnt(0)" ::: "memory");
    __syncthreads();

    int cur = 0;
    for (int kt = t0; kt <= t1; ++kt) {
        const int kb = kt * 32;
        if (kt < t1) stage((kt + 1) * 32, cur ^ 1);   // async prefetch next tile

        if ((kb <= qw + 15) && (kb + 31 >= qw - WINDOW)) {
            // ---- QK^T (swizzled K reads) ----
            f32x4 sc[2];
            __builtin_amdgcn_s_setprio(1);
#pragma unroll
            for (int ct = 0; ct < 2; ++ct) {
                f32x4 a = zero;
                const char* kbase = (const char*)&lK[cur][0] + (ct * 16 + l16) * 512;
                const unsigned swz = (unsigned)((l16 & 7) << 4);
#pragma unroll
                for (int f = 0; f < 8; ++f) {
                    bf16x8 kf = *(const bf16x8*)(
                        kbase + (((unsigned)(f * 64 + quad * 16)) ^ swz));
                    a = __builtin_amdgcn_mfma_f32_16x16x32_bf16(qf[f], kf, a, 0, 0, 0);
                }
                sc[ct] = a;
            }
            __builtin_amdgcn_s_setprio(0);

            // ---- softcap + mask ----
            float p0[4], p1[4], rowmax[4];
#pragma unroll
            for (int r = 0; r < 4; ++r) {
                const int gi = qw + quad * 4 + r;
                float x0 = 50.f * fast_tanh(sc[0][r] * 0.02f);
                float x1 = 50.f * fast_tanh(sc[1][r] * 0.02f);
                int gj0 = kb + l16, gj1 = kb + 16 + l16;
                bool ok0 = (gj0 <= gi) && (gi - gj0 <= WINDOW);
                bool ok1 = (gj1 <= gi) && (gi - gj1 <= WINDOW);
                p0[r] = ok0 ? x0 : -1e30f;
                p1[r] = ok1 ? x1 : -1e30f;
                rowmax[r] = fmaxf(p0[r], p1[r]);
            }
#pragma unroll
            for (int m = 1; m < 16; m <<= 1)
#pragma unroll
                for (int r = 0; r < 4; ++r)
                    rowmax[r] = fmaxf(rowmax[r], __shfl_xor(rowmax[r], m, 64));

            // ---- defer-max (T13, THR=8) ----
            float need = -1e30f;
#pragma unroll
            for (int r = 0; r < 4; ++r) need = fmaxf(need, rowmax[r] - m_r[r]);
            const bool upd = __any(need > 8.f) != 0;
            float al[4];
            if (upd) {
#pragma unroll
                for (int r = 0; r < 4; ++r) {
                    float mn = fmaxf(m_r[r], rowmax[r]);
                    al[r] = __expf(m_r[r] - mn);
                    m_r[r] = mn;
                }
            }

            float rs[4];
#pragma unroll
            for (int r = 0; r < 4; ++r) {
                p0[r] = __expf(p0[r] - m_r[r]);
                p1[r] = __expf(p1[r] - m_r[r]);
                rs[r] = p0[r] + p1[r];
            }
#pragma unroll
            for (int m = 1; m < 16; m <<= 1)
#pragma unroll
                for (int r = 0; r < 4; ++r)
                    rs[r] += __shfl_xor(rs[r], m, 64);

            if (upd) {
#pragma unroll
                for (int dt = 0; dt < 16; ++dt)
#pragma unroll
                    for (int r = 0; r < 4; ++r) o[dt][r] *= al[r];
#pragma unroll
                for (int r = 0; r < 4; ++r) l_r[r] = l_r[r] * al[r] + rs[r];
            } else {
#pragma unroll
                for (int r = 0; r < 4; ++r) l_r[r] += rs[r];
            }

            // ---- P: C-layout -> A-layout via per-wave LDS round-trip ----
            u16* pw = &lP[wave][0];
#pragma unroll
            for (int r = 0; r < 4; ++r) {
                pw[(quad * 4 + r) * 40 + l16]      = f2bf(p0[r]);
                pw[(quad * 4 + r) * 40 + 16 + l16] = f2bf(p1[r]);
            }
            asm volatile("s_waitcnt lgkmcnt(0)" ::: "memory");
            bf16x8 pf = *(const bf16x8*)(&pw[l16 * 40 + quad * 8]);

            // ---- PV: V^T reads (compiler-managed waits) ----
            __builtin_amdgcn_s_setprio(1);
#pragma unroll
            for (int dt = 0; dt < 16; ++dt) {
                bf16x8 vf = *(const bf16x8*)((const char*)&lV[cur][0] + dt * 1024 + vrow);
                o[dt] = __builtin_amdgcn_mfma_f32_16x16x32_bf16(pf, vf, o[dt], 0, 0, 0);
            }
            __builtin_amdgcn_s_setprio(0);
        }

        asm volatile("s_waitcnt vmcnt(0)" ::: "memory");   // next tile staged
        __syncthreads();                                    // all waves done
        cur ^= 1;
    }

    float inv_l[4];
#pragma unroll
    for (int r = 0; r < 4; ++r) inv_l[r] = 1.f / l_r[r];
#pragma unroll
    for (int dt = 0; dt < 16; ++dt)
#pragma unroll
        for (int r = 0; r < 4; ++r) {
            int grow = qbase + (wave & 3) * 16 + quad * 4 + r;
            int gcol = h * HD + dt * 16 + l16;
            O[(size_t)grow * QSZ + gcol] = f2bf(o[dt][r] * inv_l[r]);
        }
}

// ---------------- launch ----------------------------------------------------
extern "C" void kernel_launch(void* const* d_in, const int* in_sizes, int n_in,
                              void* d_out, int out_size, void* d_ws, size_t ws_size,
                              hipStream_t stream) {
    const float* hidden = (const float*)d_in[1];
    const float* w_qkv  = (const float*)d_in[2];
    const float* w_o    = (const float*)d_in[3];
    float* out = (float*)d_out;

    char* ws = (char*)d_ws;
    size_t off = 0;
    auto alloc = [&](size_t bytes) {
        void* p = ws + off; off += (bytes + 255) & ~(size_t)255; return p;
    };
    u16* Xb    = (u16*)alloc((size_t)S_LEN * HID   * 2);
    u16* Wqkvb = (u16*)alloc((size_t)QKV_N * HID   * 2);
    u16* QKVb  = (u16*)alloc((size_t)S_LEN * QKV_N * 2);
    u16* Qb    = (u16*)alloc((size_t)NH  * S_LEN * HD * 2);
    u16* Kb    = (u16*)alloc((size_t)NKV * S_LEN * HD * 2);
    u16* Vt    = (u16*)alloc((size_t)NKV * S_LEN * HD * 2);   // [h][d][s]
    u16* attn  = QKVb;   // dead after rope_split/transpose_v
    u16* Wob   = Xb;     // dead after gemm1

    const int n1 = S_LEN * HID / 4;
    const int n2 = QKV_N * HID / 4;

    cast_f32_bf16<<<dim3((n1 + 255) / 256), dim3(256), 0, stream>>>(hidden, Xb, n1);
    cast_f32_bf16<<<dim3((n2 + 255) / 256), dim3(256), 0, stream>>>(w_qkv, Wqkvb, n2);
    gemm_bt<1><<<dim3(QKV_N / 128, S_LEN / 128), dim3(256), 0, stream>>>(
        Xb, Wqkvb, (void*)QKVb, S_LEN, QKV_N, HID);
    rope_split<<<dim3(S_LEN), dim3(256), 0, stream>>>(QKVb, Qb, Kb);
    transpose_v<<<dim3(NKV, S_LEN / 64), dim3(256), 0, stream>>>(QKVb, Vt);
    cast_f32_bf16<<<dim3((n1 + 255) / 256), dim3(256), 0, stream>>>(w_o, Wob, n1);
    attn_fused<<<dim3(512), dim3(512), 0, stream>>>(Qb, Kb, Vt, attn);
    gemm_bt<0><<<dim3(HID / 128, S_LEN / 128), dim3(256), 0, stream>>>(
        attn, Wob, (void*)out, S_LEN, HID, QSZ);
}

// Round 5
// 961.137 us; speedup vs baseline: 1.1094x; 1.1094x over previous
//
#include <hip/hip_runtime.h>
#include <cstdint>
#include <cstddef>

#define S_LEN 4096
#define HID   3584
#define NH    16
#define NKV   8
#define HD    256
#define QSZ   (NH*HD)            // 4096
#define KVSZ  (NKV*HD)           // 2048
#define QKV_N (QSZ + 2*KVSZ)     // 8192
#define WINDOW 2047

typedef unsigned short u16;
typedef __bf16 bf16x8 __attribute__((ext_vector_type(8)));
typedef u16    u16x8  __attribute__((ext_vector_type(8)));
typedef u16    u16x4  __attribute__((ext_vector_type(4)));
typedef float  f32x4  __attribute__((ext_vector_type(4)));

__device__ inline float bf2f(u16 u) {
    union { unsigned u; float f; } v; v.u = ((unsigned)u) << 16; return v.f;
}
__device__ inline u16 f2bf(float f) {
    union { float f; unsigned u; } v; v.f = f;
    return (u16)((v.u + 0x7FFF + ((v.u >> 16) & 1)) >> 16);
}
// 50*tanh(s*0.02) = 50 - 100/(exp(s*0.04)+1); inf-safe at extremes.
__device__ inline float softcap50(float s) {
    float e = __expf(s * 0.04f);
    return 50.f - 100.f / (e + 1.f);
}

// ---- async global->LDS (width 16): LDS dest = wave-uniform base, HW adds
// ---- lane*16; global src per-lane (m104/m108/m201) -------------------------
typedef const __attribute__((address_space(1))) unsigned GU32;
typedef __attribute__((address_space(3))) unsigned LU32;
__device__ inline void gll16(const void* g, const void* l) {
    __builtin_amdgcn_global_load_lds((GU32*)(size_t)g,
                                     (LU32*)(unsigned)(size_t)l, 16, 0, 0);
}

// ---------------- fp32 -> bf16 cast (vectorized) ----------------
__global__ __launch_bounds__(256)
void cast_f32_bf16(const float* __restrict__ src, u16* __restrict__ dst, int n4) {
    int i = blockIdx.x * blockDim.x + threadIdx.x;
    if (i >= n4) return;
    float4 v = ((const float4*)src)[i];
    u16x4 o;
    o[0] = f2bf(v.x); o[1] = f2bf(v.y); o[2] = f2bf(v.z); o[3] = f2bf(v.w);
    ((u16x4*)dst)[i] = o;
}

// ---------------- bf16 GEMM, C[m,n] = sum_k A[m,k]*B[n,k]  (both K-major) ----
// m97 structure: 128x128 tile, BK=32, double-buffered LDS filled by
// global_load_lds width=16 (no VGPR round-trip).
template<int BF16OUT>
__global__ __launch_bounds__(256)
void gemm_bt(const u16* __restrict__ A, const u16* __restrict__ B,
             void* __restrict__ Cv, int M, int N, int K) {
    __shared__ u16 lA[2][128 * 32];
    __shared__ u16 lB[2][128 * 32];
    const int tid  = threadIdx.x;
    const int lane = tid & 63, wave = tid >> 6;
    const int quad = lane >> 4, l16 = lane & 15;
    const int m0 = blockIdx.y * 128, n0 = blockIdx.x * 128;
    const int wm = (wave & 1) * 64, wn = (wave >> 1) * 64;

    f32x4 zero = {0.f, 0.f, 0.f, 0.f};
    f32x4 acc[4][4];
#pragma unroll
    for (int i = 0; i < 4; ++i)
#pragma unroll
        for (int j = 0; j < 4; ++j) acc[i][j] = zero;

    // staging: chunk c (0..511) -> row c>>2, col (c&3)*8; LDS byte c*16.
    const int c0 = tid, c1 = tid + 256;
    const u16* A0 = A + (size_t)(m0 + (c0 >> 2)) * K + (c0 & 3) * 8;
    const u16* A1 = A + (size_t)(m0 + (c1 >> 2)) * K + (c1 & 3) * 8;
    const u16* B0 = B + (size_t)(n0 + (c0 >> 2)) * K + (c0 & 3) * 8;
    const u16* B1 = B + (size_t)(n0 + (c1 >> 2)) * K + (c1 & 3) * 8;
    const int wb0 = wave * 1024, wb1 = 4096 + wave * 1024;  // wave-uniform dests

    auto stage = [&](int k0, int b) {
        gll16(A0 + k0, (const char*)&lA[b][0] + wb0);
        gll16(A1 + k0, (const char*)&lA[b][0] + wb1);
        gll16(B0 + k0, (const char*)&lB[b][0] + wb0);
        gll16(B1 + k0, (const char*)&lB[b][0] + wb1);
    };

    stage(0, 0);
    asm volatile("s_waitcnt vmcnt(0)" ::: "memory");
    __syncthreads();

    int cur = 0;
    for (int k0 = 0; k0 < K; k0 += 32) {
        if (k0 + 32 < K) stage(k0 + 32, cur ^ 1);   // async prefetch next slice

        bf16x8 af[4], bfr[4];
#pragma unroll
        for (int mt = 0; mt < 4; ++mt)
            af[mt] = *(const bf16x8*)(&lA[cur][(wm + mt * 16 + l16) * 32 + quad * 8]);
#pragma unroll
        for (int nt = 0; nt < 4; ++nt)
            bfr[nt] = *(const bf16x8*)(&lB[cur][(wn + nt * 16 + l16) * 32 + quad * 8]);
        __builtin_amdgcn_s_setprio(1);
#pragma unroll
        for (int mt = 0; mt < 4; ++mt)
#pragma unroll
            for (int nt = 0; nt < 4; ++nt)
                acc[mt][nt] = __builtin_amdgcn_mfma_f32_16x16x32_bf16(
                    af[mt], bfr[nt], acc[mt][nt], 0, 0, 0);
        __builtin_amdgcn_s_setprio(0);

        asm volatile("s_waitcnt vmcnt(0)" ::: "memory");
        __syncthreads();
        cur ^= 1;
    }

#pragma unroll
    for (int mt = 0; mt < 4; ++mt)
#pragma unroll
        for (int nt = 0; nt < 4; ++nt)
#pragma unroll
            for (int r = 0; r < 4; ++r) {
                int row = m0 + wm + mt * 16 + quad * 4 + r;
                int col = n0 + wn + nt * 16 + l16;
                float v = acc[mt][nt][r];
                if (BF16OUT) ((u16*)Cv)[(size_t)row * N + col] = f2bf(v);
                else         ((float*)Cv)[(size_t)row * N + col] = v;
            }
}

// ---------------- RoPE (NeoX) + split + per-head relayout (Q,K only) --------
__global__ __launch_bounds__(256)
void rope_split(const u16* __restrict__ qkv, u16* __restrict__ Qb,
                u16* __restrict__ Kb) {
    const int s = blockIdx.x;
    const int t = threadIdx.x;
    const float pos = (float)s;
    const u16* row = qkv + (size_t)s * QKV_N;

    for (int p = t; p < 2048; p += 256) {      // Q: 16 heads x 128 pairs
        int h = p >> 7, d = p & 127;
        float inv = __expf(-(float)d * 0.0719557841560639f);  // ln(1e4)/128
        float ang = pos * inv, sn, cs;
        sincosf(ang, &sn, &cs);
        float x1 = bf2f(row[h * HD + d]);
        float x2 = bf2f(row[h * HD + d + 128]);
        size_t base = ((size_t)h * S_LEN + s) * HD;
        Qb[base + d]       = f2bf((x1 * cs - x2 * sn) * 0.0625f);
        Qb[base + d + 128] = f2bf((x2 * cs + x1 * sn) * 0.0625f);
    }
    for (int p = t; p < 1024; p += 256) {      // K: 8 heads x 128 pairs
        int h = p >> 7, d = p & 127;
        float inv = __expf(-(float)d * 0.0719557841560639f);
        float ang = pos * inv, sn, cs;
        sincosf(ang, &sn, &cs);
        float x1 = bf2f(row[QSZ + h * HD + d]);
        float x2 = bf2f(row[QSZ + h * HD + d + 128]);
        size_t base = ((size_t)h * S_LEN + s) * HD;
        Kb[base + d]       = f2bf(x1 * cs - x2 * sn);
        Kb[base + d + 128] = f2bf(x2 * cs + x1 * sn);
    }
}

// ---------------- V transpose: QKVb[s][...] -> Vt[h][d][s] ------------------
__global__ __launch_bounds__(256)
void transpose_v(const u16* __restrict__ qkv, u16* __restrict__ Vt) {
    const int h = blockIdx.x, s0 = blockIdx.y * 64;
    const int tid = threadIdx.x;
    __shared__ u16 t[64 * 258];
    const u16* src = qkv + QSZ + KVSZ + (size_t)h * HD;
#pragma unroll
    for (int it = 0; it < 8; ++it) {
        int idx = it * 256 + tid;                 // 2048 chunks of 8
        int sr = idx >> 5, c8 = (idx & 31) << 3;
        u16x8 v = *(const u16x8*)(src + (size_t)(s0 + sr) * QKV_N + c8);
#pragma unroll
        for (int j = 0; j < 8; ++j) t[sr * 258 + c8 + j] = v[j];
    }
    __syncthreads();
    const int lane = tid & 63, wave = tid >> 6;
    u16* dst = Vt + (size_t)h * HD * S_LEN + s0 + lane;
#pragma unroll
    for (int it = 0; it < 64; ++it) {
        int d = it * 4 + wave;
        dst[(size_t)d * S_LEN] = t[lane * 258 + d];
    }
}

// ---------------- fused sliding-window softcap attention --------------------
// 1-D grid of 512; hkv = bid & 7 keeps one GQA pair's K/V slab on one XCD's L2.
// 8 waves: wave>>2 = q-head of pair, wave&3 = 16-row q-slice.
// Fast path has ZERO cross-lane reductions: defer-max check via __any on
// lane-local maxima; l_r kept as lane-local partials, reduced in epilogue.
__global__ __launch_bounds__(512)
void attn_fused(const u16* __restrict__ Qb, const u16* __restrict__ Kb,
                const u16* __restrict__ Vt, u16* __restrict__ O) {
    const int bid = blockIdx.x;
    const int hkv = bid & 7;
    const int qt  = bid >> 3;
    const int qbase = qt * 64;
    const int tid = threadIdx.x, wave = tid >> 6, lane = tid & 63;
    const int quad = lane >> 4, l16 = lane & 15;
    const int h  = hkv * 2 + (wave >> 2);
    const int qw = qbase + (wave & 3) * 16;

    __shared__ __align__(16) u16 lK[2][32 * 256];   // 2 x 16 KB, XOR-swz rows
    __shared__ __align__(16) u16 lV[2][32 * 256];   // 2 x 16 KB (V^T, swz chunks)
    __shared__ __align__(16) u16 lP[8][16 * 40];    // per-wave P scratch

    bf16x8 qf[8];
    {
        const u16* qp = Qb + ((size_t)h * S_LEN + qw + l16) * HD + quad * 8;
#pragma unroll
        for (int f = 0; f < 8; ++f) qf[f] = *(const bf16x8*)(qp + f * 32);
    }

    int koff[2], voff[2];
#pragma unroll
    for (int i = 0; i < 2; ++i) {
        int c = i * 512 + tid;                    // chunk 0..1023
        int row = c >> 5, j = c & 31;
        koff[i] = row * 512 + ((j ^ (row & 7)) << 4);
        int d = c >> 2;
        int q = (c & 3) ^ ((d >> 1) & 3);
        voff[i] = d * (S_LEN * 2) + q * 16;       // bytes into Vt head slab
    }
    const char* Khb = (const char*)(Kb + (size_t)hkv * S_LEN * HD);
    const char* Vhb = (const char*)(Vt + (size_t)hkv * HD * S_LEN);

    const unsigned vrow = (unsigned)(l16 * 64)
                        + ((unsigned)(quad ^ ((l16 >> 1) & 3)) << 4);

    f32x4 zero = {0.f, 0.f, 0.f, 0.f};
    f32x4 o[16];
#pragma unroll
    for (int i = 0; i < 16; ++i) o[i] = zero;
    float m_r[4], l_r[4];
#pragma unroll
    for (int r = 0; r < 4; ++r) { m_r[r] = -1e4f; l_r[r] = 0.f; }

    const int t0 = max(0, qbase - WINDOW) >> 5;
    const int t1 = (qbase + 63) >> 5;

    auto stage = [&](int kb, int b) {
        const char* kp = Khb + ((size_t)kb << 9);
        const char* vp = Vhb + ((size_t)kb << 1);
#pragma unroll
        for (int i = 0; i < 2; ++i) {
            gll16(kp + koff[i], (const char*)&lK[b][0] + i * 8192 + wave * 1024);
            gll16(vp + voff[i], (const char*)&lV[b][0] + i * 8192 + wave * 1024);
        }
    };

    stage(t0 * 32, 0);
    asm volatile("s_waitcnt vmcnt(0)" ::: "memory");
    __syncthreads();

    int cur = 0;
    for (int kt = t0; kt <= t1; ++kt) {
        const int kb = kt * 32;
        if (kt < t1) stage((kt + 1) * 32, cur ^ 1);   // async prefetch next tile

        if ((kb <= qw + 15) && (kb + 31 >= qw - WINDOW)) {
            // ---- QK^T (swizzled K reads) ----
            f32x4 sc[2];
            __builtin_amdgcn_s_setprio(1);
#pragma unroll
            for (int ct = 0; ct < 2; ++ct) {
                f32x4 a = zero;
                const char* kbase = (const char*)&lK[cur][0] + (ct * 16 + l16) * 512;
                const unsigned swz = (unsigned)((l16 & 7) << 4);
#pragma unroll
                for (int f = 0; f < 8; ++f) {
                    bf16x8 kf = *(const bf16x8*)(
                        kbase + (((unsigned)(f * 64 + quad * 16)) ^ swz));
                    a = __builtin_amdgcn_mfma_f32_16x16x32_bf16(qf[f], kf, a, 0, 0, 0);
                }
                sc[ct] = a;
            }
            __builtin_amdgcn_s_setprio(0);

            // ---- softcap (+ mask only on boundary tiles) ----
            float p0[4], p1[4];
            const bool interior = (kb + 31 <= qw) && (kb + WINDOW >= qw + 15);
            if (interior) {
#pragma unroll
                for (int r = 0; r < 4; ++r) {
                    p0[r] = softcap50(sc[0][r]);
                    p1[r] = softcap50(sc[1][r]);
                }
            } else {
#pragma unroll
                for (int r = 0; r < 4; ++r) {
                    const int gi = qw + quad * 4 + r;
                    float x0 = softcap50(sc[0][r]);
                    float x1 = softcap50(sc[1][r]);
                    int gj0 = kb + l16, gj1 = kb + 16 + l16;
                    bool ok0 = (gj0 <= gi) && (gi - gj0 <= WINDOW);
                    bool ok1 = (gj1 <= gi) && (gi - gj1 <= WINDOW);
                    p0[r] = ok0 ? x0 : -1e30f;
                    p1[r] = ok1 ? x1 : -1e30f;
                }
            }

            // ---- defer-max check: NO reduction tree on fast path ----
            float need = -1e30f;
#pragma unroll
            for (int r = 0; r < 4; ++r)
                need = fmaxf(need, fmaxf(p0[r], p1[r]) - m_r[r]);
            const bool upd = __any(need > 8.f) != 0;
            if (upd) {                 // rare: exact rowmax + rescale
                float rowmax[4];
#pragma unroll
                for (int r = 0; r < 4; ++r) rowmax[r] = fmaxf(p0[r], p1[r]);
#pragma unroll
                for (int m = 1; m < 16; m <<= 1)
#pragma unroll
                    for (int r = 0; r < 4; ++r)
                        rowmax[r] = fmaxf(rowmax[r], __shfl_xor(rowmax[r], m, 64));
                float al[4];
#pragma unroll
                for (int r = 0; r < 4; ++r) {
                    float mn = fmaxf(m_r[r], rowmax[r]);
                    al[r] = __expf(m_r[r] - mn);
                    m_r[r] = mn;
                    l_r[r] *= al[r];
                }
#pragma unroll
                for (int dt = 0; dt < 16; ++dt)
#pragma unroll
                    for (int r = 0; r < 4; ++r) o[dt][r] *= al[r];
            }

#pragma unroll
            for (int r = 0; r < 4; ++r) {
                p0[r] = __expf(p0[r] - m_r[r]);
                p1[r] = __expf(p1[r] - m_r[r]);
                l_r[r] += p0[r] + p1[r];      // lane-local partial sum
            }

            // ---- P -> bf16 (cvt_pk) -> per-wave LDS A-layout round-trip ----
            u16* pw = &lP[wave][0];
#pragma unroll
            for (int r = 0; r < 4; ++r) {
                unsigned pk;
                asm("v_cvt_pk_bf16_f32 %0, %1, %2"
                    : "=v"(pk) : "v"(p0[r]), "v"(p1[r]));
                pw[(quad * 4 + r) * 40 + l16]      = (u16)pk;
                pw[(quad * 4 + r) * 40 + 16 + l16] = (u16)(pk >> 16);
            }
            asm volatile("s_waitcnt lgkmcnt(0)" ::: "memory");
            bf16x8 pf = *(const bf16x8*)(&pw[l16 * 40 + quad * 8]);

            // ---- PV ----
            __builtin_amdgcn_s_setprio(1);
#pragma unroll
            for (int dt = 0; dt < 16; ++dt) {
                bf16x8 vf = *(const bf16x8*)((const char*)&lV[cur][0] + dt * 1024 + vrow);
                o[dt] = __builtin_amdgcn_mfma_f32_16x16x32_bf16(pf, vf, o[dt], 0, 0, 0);
            }
            __builtin_amdgcn_s_setprio(0);
        }

        asm volatile("s_waitcnt vmcnt(0)" ::: "memory");   // next tile staged
        __syncthreads();
        cur ^= 1;
    }

    // epilogue: reduce lane-local l partials across the 16-lane col groups
#pragma unroll
    for (int m = 1; m < 16; m <<= 1)
#pragma unroll
        for (int r = 0; r < 4; ++r)
            l_r[r] += __shfl_xor(l_r[r], m, 64);
    float inv_l[4];
#pragma unroll
    for (int r = 0; r < 4; ++r) inv_l[r] = 1.f / l_r[r];
#pragma unroll
    for (int dt = 0; dt < 16; ++dt)
#pragma unroll
        for (int r = 0; r < 4; ++r) {
            int grow = qbase + (wave & 3) * 16 + quad * 4 + r;
            int gcol = h * HD + dt * 16 + l16;
            O[(size_t)grow * QSZ + gcol] = f2bf(o[dt][r] * inv_l[r]);
        }
}

// ---------------- launch ----------------------------------------------------
extern "C" void kernel_launch(void* const* d_in, const int* in_sizes, int n_in,
                              void* d_out, int out_size, void* d_ws, size_t ws_size,
                              hipStream_t stream) {
    const float* hidden = (const float*)d_in[1];
    const float* w_qkv  = (const float*)d_in[2];
    const float* w_o    = (const float*)d_in[3];
    float* out = (float*)d_out;

    char* ws = (char*)d_ws;
    size_t off = 0;
    auto alloc = [&](size_t bytes) {
        void* p = ws + off; off += (bytes + 255) & ~(size_t)255; return p;
    };
    u16* Xb    = (u16*)alloc((size_t)S_LEN * HID   * 2);
    u16* Wqkvb = (u16*)alloc((size_t)QKV_N * HID   * 2);
    u16* QKVb  = (u16*)alloc((size_t)S_LEN * QKV_N * 2);
    u16* Qb    = (u16*)alloc((size_t)NH  * S_LEN * HD * 2);
    u16* Kb    = (u16*)alloc((size_t)NKV * S_LEN * HD * 2);
    u16* Vt    = (u16*)alloc((size_t)NKV * S_LEN * HD * 2);   // [h][d][s]
    u16* attn  = QKVb;   // dead after rope_split/transpose_v
    u16* Wob   = Xb;     // dead after gemm1

    const int n1 = S_LEN * HID / 4;
    const int n2 = QKV_N * HID / 4;

    cast_f32_bf16<<<dim3((n1 + 255) / 256), dim3(256), 0, stream>>>(hidden, Xb, n1);
    cast_f32_bf16<<<dim3((n2 + 255) / 256), dim3(256), 0, stream>>>(w_qkv, Wqkvb, n2);
    gemm_bt<1><<<dim3(QKV_N / 128, S_LEN / 128), dim3(256), 0, stream>>>(
        Xb, Wqkvb, (void*)QKVb, S_LEN, QKV_N, HID);
    rope_split<<<dim3(S_LEN), dim3(256), 0, stream>>>(QKVb, Qb, Kb);
    transpose_v<<<dim3(NKV, S_LEN / 64), dim3(256), 0, stream>>>(QKVb, Vt);
    cast_f32_bf16<<<dim3((n1 + 255) / 256), dim3(256), 0, stream>>>(w_o, Wob, n1);
    attn_fused<<<dim3(512), dim3(512), 0, stream>>>(Qb, Kb, Vt, attn);
    gemm_bt<0><<<dim3(HID / 128, S_LEN / 128), dim3(256), 0, stream>>>(
        attn, Wob, (void*)out, S_LEN, HID, QSZ);
}